// Round 1
// baseline (629.998 us; speedup 1.0000x reference)
//
#include <hip/hip_runtime.h>
#include <stdint.h>

typedef unsigned short u16;
typedef short v8s __attribute__((ext_vector_type(8)));
typedef short v4s __attribute__((ext_vector_type(4)));
typedef float v4f __attribute__((ext_vector_type(4)));

#define NB 32768
#define ND 256
#define DTF (1.0f/3.0f)
#define ALPHA 0.1f
#define DECAY 0.99f
#define TAU_MIN 0.2f
// ETA * (MOE_WEIGHT/STEPS) / B
#define HEBB_SCALE (0.1f*(1.0f/3.0f)/32768.0f)

__device__ __forceinline__ float b2f(u16 h){ return __uint_as_float(((unsigned)h)<<16); }
__device__ __forceinline__ u16 f2b(float f){
  unsigned u = __float_as_uint(f);
  u += 0x7FFFu + ((u>>16)&1u);
  return (u16)(u>>16);
}

// ---------------- init: x -> bf16 copy, h -> f32 state ----------------
__global__ void k_copy(const float* __restrict__ x, const float* __restrict__ h,
                       u16* __restrict__ x_bf, float* __restrict__ h_state){
  const long tot = (long)NB*ND/4;
  for (long i = blockIdx.x*(long)blockDim.x + threadIdx.x; i < tot;
       i += (long)gridDim.x*blockDim.x){
    v4f xv = *(const v4f*)(x + 4*i);
    u16 t4[4];
#pragma unroll
    for (int e=0;e<4;++e) t4[e] = f2b(xv[e]);
    *(v4s*)(x_bf + 4*i) = *(v4s*)t4;
    *(v4f*)(h_state + 4*i) = *(const v4f*)(h + 4*i);
  }
}

// ---------------- x -> xT (bf16, [i][b]) via LDS tile transpose ----------------
__global__ void k_transpose_x(const float* __restrict__ x, u16* __restrict__ xT){
  __shared__ u16 ld[64*65];
  int bt = blockIdx.x >> 2, it = blockIdx.x & 3;
  long b0 = (long)bt*64; int i0 = it*64;
  int t = threadIdx.x;
#pragma unroll
  for (int e=0;e<16;++e){
    int idx = e*256 + t; int r = idx>>6, c = idx&63;
    ld[c + r*65] = f2b(x[(b0+r)*ND + i0 + c]);
  }
  __syncthreads();
#pragma unroll
  for (int e=0;e<16;++e){
    int idx = e*256 + t; int rr = idx>>6, cc = idx&63;
    xT[(long)(i0+rr)*NB + b0 + cc] = ld[cc*65 + rr];
  }
}

// ---------------- weight prep (bf16 [n][k] layouts) ----------------
__global__ void k_prep_w(const float* __restrict__ W_ih, const float* __restrict__ W_hh,
                         const float* __restrict__ W_t1, const float* __restrict__ W_t2,
                         const float* __restrict__ hebb_ih, const float* __restrict__ hebb_hh,
                         u16* __restrict__ weff_ih, u16* __restrict__ weff_hh,
                         u16* __restrict__ wt1a, u16* __restrict__ wt1b, u16* __restrict__ wt2){
  int i = blockIdx.x*blockDim.x + threadIdx.x;
  if (i >= ND*ND) return;
  int n = i >> 8, k = i & 255;
  weff_ih[i] = f2b(W_ih[i] + ALPHA*hebb_ih[k*ND + n]);
  weff_hh[i] = f2b(W_hh[i] + ALPHA*hebb_hh[k*ND + n]);
  wt1a[i] = f2b(W_t1[n*512 + k]);
  wt1b[i] = f2b(W_t1[n*512 + 256 + k]);
  wt2[i]  = f2b(W_t2[i]);
}

// ---------------- P = x @ W_t1a^T + b_t1  (bf16 out) ----------------
__launch_bounds__(512,2)
__global__ void k_gemmP(const u16* __restrict__ x_bf, const u16* __restrict__ wt1a,
                        const float* __restrict__ b_t1, u16* __restrict__ P){
  __shared__ u16 lA[128*40];
  __shared__ u16 lB[256*40];
  int t = threadIdx.x, lid = t&63, wid = t>>6, wm = wid>>2, wn = wid&3, lr = lid&15, lg = lid>>4;
  long row0 = (long)blockIdx.x*128;
  v4f z = {0.f,0.f,0.f,0.f};
  v4f acc[4][4];
#pragma unroll
  for (int a=0;a<4;++a)
#pragma unroll
    for (int b=0;b<4;++b) acc[a][b] = z;
  for (int c=0; c<8; ++c){
    __syncthreads();
    { int r=t>>2, sg=t&3;
      *(v8s*)&lA[r*40+sg*8] = *(const v8s*)(x_bf + (row0+r)*ND + c*32 + sg*8); }
#pragma unroll
    for (int it2=0; it2<2; ++it2){
      int s2=t+it2*512; int n=s2>>2, sg=s2&3;
      *(v8s*)&lB[n*40+sg*8] = *(const v8s*)(wt1a + n*ND + c*32 + sg*8);
    }
    __syncthreads();
    v8s a[4], b[4];
#pragma unroll
    for (int mf=0;mf<4;++mf) a[mf] = *(v8s*)&lA[(wm*64+mf*16+lr)*40 + lg*8];
#pragma unroll
    for (int nf=0;nf<4;++nf) b[nf] = *(v8s*)&lB[(wn*64+nf*16+lr)*40 + lg*8];
#pragma unroll
    for (int mf=0;mf<4;++mf)
#pragma unroll
      for (int nf=0;nf<4;++nf)
        acc[mf][nf] = __builtin_amdgcn_mfma_f32_16x16x32_bf16(a[mf], b[nf], acc[mf][nf], 0,0,0);
  }
#pragma unroll
  for (int mf=0;mf<4;++mf)
#pragma unroll
    for (int nf=0;nf<4;++nf)
#pragma unroll
      for (int r=0;r<4;++r){
        int rr = wm*64+mf*16+lg*4+r, cc = wn*64+nf*16+lr;
        P[(row0+rr)*ND + cc] = f2b(acc[mf][nf][r] + b_t1[cc]);
      }
}

// ---------------- fused dynamics + RK update ----------------
__launch_bounds__(512,2)
__global__ void k_dyn(const u16* __restrict__ x_bf, const float* __restrict__ evalF,
                      const float* __restrict__ baseF,
                      const u16* __restrict__ weff_ih, const u16* __restrict__ weff_hh,
                      const u16* __restrict__ wt1b, const u16* __restrict__ wt2,
                      const u16* __restrict__ P,
                      const float* __restrict__ b_ih, const float* __restrict__ b_hh,
                      const float* __restrict__ b_t2,
                      float coef, float* __restrict__ outF, u16* __restrict__ outT, int writeT){
  __shared__ u16 lA[128*40];
  __shared__ u16 lB[256*40];
  __shared__ u16 lU[35840];          // phase3 A-panel [128][280]; reused [256][136] for transpose out
  __shared__ float sb1[256];
  __shared__ float sb2[256];
  int t = threadIdx.x, lid = t&63, wid = t>>6, wm = wid>>2, wn = wid&3, lr = lid&15, lg = lid>>4;
  long row0 = (long)blockIdx.x*128;
  if (t < 256){ sb1[t] = b_ih[t] + b_hh[t]; sb2[t] = b_t2[t]; }
  v4f z = {0.f,0.f,0.f,0.f};
  v4f accI[4][4], acc2[4][4];
#pragma unroll
  for (int a=0;a<4;++a)
#pragma unroll
    for (int b=0;b<4;++b){ accI[a][b] = z; acc2[a][b] = z; }

  // PHASE 1: interaction pre-act = x@weff_ih + eval@weff_hh   (16 k-chunks of 32)
  for (int c=0; c<16; ++c){
    __syncthreads();
    { int r=t>>2, sg=t&3;
      if (c < 8){
        *(v8s*)&lA[r*40+sg*8] = *(const v8s*)(x_bf + (row0+r)*ND + c*32 + sg*8);
      } else {
        const float* s = evalF + (row0+r)*ND + (c-8)*32 + sg*8;
        v4f v0 = *(const v4f*)s, v1 = *(const v4f*)(s+4);
        u16 tmp[8];
#pragma unroll
        for (int e=0;e<4;++e){ tmp[e]=f2b(v0[e]); tmp[4+e]=f2b(v1[e]); }
        *(v8s*)&lA[r*40+sg*8] = *(v8s*)tmp;
      }
    }
    const u16* W = (c<8) ? weff_ih : weff_hh;
    int ck = (c & 7)*32;
#pragma unroll
    for (int it2=0; it2<2; ++it2){
      int s2=t+it2*512; int n=s2>>2, sg=s2&3;
      *(v8s*)&lB[n*40+sg*8] = *(const v8s*)(W + n*ND + ck + sg*8);
    }
    __syncthreads();
    v8s a[4], b[4];
#pragma unroll
    for (int mf=0;mf<4;++mf) a[mf] = *(v8s*)&lA[(wm*64+mf*16+lr)*40 + lg*8];
#pragma unroll
    for (int nf=0;nf<4;++nf) b[nf] = *(v8s*)&lB[(wn*64+nf*16+lr)*40 + lg*8];
#pragma unroll
    for (int mf=0;mf<4;++mf)
#pragma unroll
      for (int nf=0;nf<4;++nf)
        accI[mf][nf] = __builtin_amdgcn_mfma_f32_16x16x32_bf16(a[mf], b[nf], accI[mf][nf], 0,0,0);
  }

  // PHASE 2: t1 pre-act = eval@wt1b  (P added in u-epilogue)
  for (int c=0; c<8; ++c){
    __syncthreads();
    { int r=t>>2, sg=t&3;
      const float* s = evalF + (row0+r)*ND + c*32 + sg*8;
      v4f v0 = *(const v4f*)s, v1 = *(const v4f*)(s+4);
      u16 tmp[8];
#pragma unroll
      for (int e=0;e<4;++e){ tmp[e]=f2b(v0[e]); tmp[4+e]=f2b(v1[e]); }
      *(v8s*)&lA[r*40+sg*8] = *(v8s*)tmp;
    }
#pragma unroll
    for (int it2=0; it2<2; ++it2){
      int s2=t+it2*512; int n=s2>>2, sg=s2&3;
      *(v8s*)&lB[n*40+sg*8] = *(const v8s*)(wt1b + n*ND + c*32 + sg*8);
    }
    __syncthreads();
    v8s a[4], b[4];
#pragma unroll
    for (int mf=0;mf<4;++mf) a[mf] = *(v8s*)&lA[(wm*64+mf*16+lr)*40 + lg*8];
#pragma unroll
    for (int nf=0;nf<4;++nf) b[nf] = *(v8s*)&lB[(wn*64+nf*16+lr)*40 + lg*8];
#pragma unroll
    for (int mf=0;mf<4;++mf)
#pragma unroll
      for (int nf=0;nf<4;++nf)
        acc2[mf][nf] = __builtin_amdgcn_mfma_f32_16x16x32_bf16(a[mf], b[nf], acc2[mf][nf], 0,0,0);
  }

  // u = SiLU(acc2 + P)  ->  lU [128][280]
#pragma unroll
  for (int mf=0;mf<4;++mf)
#pragma unroll
    for (int nf=0;nf<4;++nf)
#pragma unroll
      for (int r=0;r<4;++r){
        int rr = wm*64+mf*16+lg*4+r, cc = wn*64+nf*16+lr;
        float v = acc2[mf][nf][r] + b2f(P[(row0+rr)*ND + cc]);
        float sgm = 1.f/(1.f + __expf(-v));
        lU[rr*280 + cc] = f2b(v*sgm);
      }

  // PHASE 3: t2 pre-act = u@wt2
  v4f acc4[4][4];
#pragma unroll
  for (int a=0;a<4;++a)
#pragma unroll
    for (int b=0;b<4;++b) acc4[a][b] = z;
  for (int c=0; c<8; ++c){
    __syncthreads();   // first iter: publishes lU; also protects lB reuse
#pragma unroll
    for (int it2=0; it2<2; ++it2){
      int s2=t+it2*512; int n=s2>>2, sg=s2&3;
      *(v8s*)&lB[n*40+sg*8] = *(const v8s*)(wt2 + n*ND + c*32 + sg*8);
    }
    __syncthreads();
    v8s a[4], b[4];
#pragma unroll
    for (int mf=0;mf<4;++mf) a[mf] = *(v8s*)&lU[(wm*64+mf*16+lr)*280 + c*32 + lg*8];
#pragma unroll
    for (int nf=0;nf<4;++nf) b[nf] = *(v8s*)&lB[(wn*64+nf*16+lr)*40 + lg*8];
#pragma unroll
    for (int mf=0;mf<4;++mf)
#pragma unroll
      for (int nf=0;nf<4;++nf)
        acc4[mf][nf] = __builtin_amdgcn_mfma_f32_16x16x32_bf16(a[mf], b[nf], acc4[mf][nf], 0,0,0);
  }

  __syncthreads();  // all lU reads done before reuse as transpose staging
  // epilogue: inter = tanh(accI + b), tau = softplus(acc4 + b_t2) + TAU_MIN
  //           out = base + coef*(inter - eval)/tau
#pragma unroll
  for (int mf=0;mf<4;++mf)
#pragma unroll
    for (int nf=0;nf<4;++nf)
#pragma unroll
      for (int r=0;r<4;++r){
        int rr = wm*64+mf*16+lg*4+r, cc = wn*64+nf*16+lr;
        long gi = (row0+rr)*ND + cc;
        float pre = accI[mf][nf][r] + sb1[cc];
        float pc = fminf(fmaxf(pre, -15.f), 15.f);
        float e2 = __expf(2.f*pc);
        float inter = (e2 - 1.f)/(e2 + 1.f);
        float zz = acc4[mf][nf][r] + sb2[cc];
        float sp = (zz > 15.f) ? zz : __logf(1.f + __expf(zz));
        float tau = sp + TAU_MIN;
        float ev = evalF[gi];
        float o = baseF[gi] + coef*(inter - ev)/tau;
        outF[gi] = o;
        if (writeT) lU[cc*136 + rr] = f2b(o);
      }
  if (writeT){
    __syncthreads();
    int cc = t>>1, r0 = (t&1)*64;
#pragma unroll
    for (int e=0;e<8;++e){
      v8s v = *(v8s*)&lU[cc*136 + r0 + e*8];
      *(v8s*)(outT + (long)cc*NB + row0 + r0 + e*8) = v;
    }
  }
}

// ---------------- hebb partial:  part[blk] = A^T-chunk @ m-chunk  ----------------
__launch_bounds__(512,2)
__global__ void k_hebb_part(const u16* __restrict__ xT, const u16* __restrict__ hmT,
                            u16* __restrict__ part){
  __shared__ u16 lA[256*40];
  __shared__ u16 lB[256*40];
  int t = threadIdx.x, lid = t&63, wid = t>>6, wm = wid>>2, wn = wid&3, lr = lid&15, lg = lid>>4;
  int mat = blockIdx.x & 1, chunk = blockIdx.x >> 1;
  const u16* Asrc = mat ? hmT : xT;
  v4f z = {0.f,0.f,0.f,0.f};
  v4f acc[8][4];
#pragma unroll
  for (int a=0;a<8;++a)
#pragma unroll
    for (int b=0;b<4;++b) acc[a][b] = z;
  for (int kc=0; kc<8; ++kc){
    long b0 = (long)chunk*256 + kc*32;
    __syncthreads();
#pragma unroll
    for (int it2=0; it2<2; ++it2){
      int s = t + it2*512; int rr = s>>2, sg = s&3;
      *(v8s*)&lA[rr*40+sg*8] = *(const v8s*)(Asrc + (long)rr*NB + b0 + sg*8);
      *(v8s*)&lB[rr*40+sg*8] = *(const v8s*)(hmT  + (long)rr*NB + b0 + sg*8);
    }
    __syncthreads();
    v8s a[8], b[4];
#pragma unroll
    for (int mf=0;mf<8;++mf) a[mf] = *(v8s*)&lA[(wm*128+mf*16+lr)*40 + lg*8];
#pragma unroll
    for (int nf=0;nf<4;++nf) b[nf] = *(v8s*)&lB[(wn*64+nf*16+lr)*40 + lg*8];
#pragma unroll
    for (int mf=0;mf<8;++mf)
#pragma unroll
      for (int nf=0;nf<4;++nf)
        acc[mf][nf] = __builtin_amdgcn_mfma_f32_16x16x32_bf16(a[mf], b[nf], acc[mf][nf], 0,0,0);
  }
  u16* dst = part + (long)blockIdx.x*65536;
#pragma unroll
  for (int mf=0;mf<8;++mf)
#pragma unroll
    for (int nf=0;nf<4;++nf)
#pragma unroll
      for (int r=0;r<4;++r){
        int i = wm*128+mf*16+lg*4+r, j = wn*64+nf*16+lr;
        dst[i*ND + j] = f2b(acc[mf][nf][r]);
      }
}

// ---------------- hebb reduce + Weff rebuild ----------------
__global__ void k_hebb_reduce(const u16* __restrict__ part,
                              const float* __restrict__ prev_ih, const float* __restrict__ prev_hh,
                              float* __restrict__ next_ih, float* __restrict__ next_hh,
                              const float* __restrict__ W_ih, const float* __restrict__ W_hh,
                              u16* __restrict__ weff_ih, u16* __restrict__ weff_hh){
  int tid = blockIdx.x*blockDim.x + threadIdx.x;
  if (tid >= 2*ND*ND) return;
  int mat = tid >> 16;
  int rem = tid & 65535;
  float s = 0.f;
  for (int c=0; c<128; ++c) s += b2f(part[(long)((c<<1)+mat)*65536 + rem]);
  const float* prev = mat ? prev_hh : prev_ih;
  float nv = DECAY*prev[rem] + HEBB_SCALE*s;
  if (mat) next_hh[rem] = nv; else next_ih[rem] = nv;
  int k = rem >> 8, n = rem & 255;
  const float* Wb = mat ? W_hh : W_ih;
  u16 wv = f2b(Wb[n*ND + k] + ALPHA*nv);
  if (mat) weff_hh[n*ND + k] = wv; else weff_ih[n*ND + k] = wv;
}

// ---------------- launcher ----------------
extern "C" void kernel_launch(void* const* d_in, const int* in_sizes, int n_in,
                              void* d_out, int out_size, void* d_ws, size_t ws_size,
                              hipStream_t stream) {
  const float* x       = (const float*)d_in[0];
  const float* h       = (const float*)d_in[1];
  const float* hebb_ih = (const float*)d_in[2];
  const float* hebb_hh = (const float*)d_in[3];
  const float* W_ih    = (const float*)d_in[4];
  const float* b_ih    = (const float*)d_in[5];
  const float* W_hh    = (const float*)d_in[6];
  const float* b_hh    = (const float*)d_in[7];
  const float* W_t1    = (const float*)d_in[8];
  const float* b_t1    = (const float*)d_in[9];
  const float* W_t2    = (const float*)d_in[10];
  const float* b_t2    = (const float*)d_in[11];
  float* h_state = (float*)d_out;

  char* w = (char*)d_ws;
  u16* x_bf = (u16*)w;  w += 16777216;
  u16* xT   = (u16*)w;  w += 16777216;
  u16* P    = (u16*)w;  w += 16777216;
  u16* hmT  = (u16*)w;  w += 16777216;
  float* hmF = (float*)w; w += 33554432;
  u16* part = (u16*)w;  w += 33554432;
  float* hebA_ih = (float*)w; w += 262144;
  float* hebA_hh = (float*)w; w += 262144;
  float* hebB_ih = (float*)w; w += 262144;
  float* hebB_hh = (float*)w; w += 262144;
  u16* weff_ih = (u16*)w; w += 131072;
  u16* weff_hh = (u16*)w; w += 131072;
  u16* wt1a    = (u16*)w; w += 131072;
  u16* wt1b    = (u16*)w; w += 131072;
  u16* wt2     = (u16*)w; w += 131072;
  if ((size_t)(w - (char*)d_ws) > ws_size) return;  // visible failure if ws too small

  k_copy<<<2048,256,0,stream>>>(x, h, x_bf, h_state);
  k_transpose_x<<<2048,256,0,stream>>>(x, xT);
  k_prep_w<<<256,256,0,stream>>>(W_ih,W_hh,W_t1,W_t2,hebb_ih,hebb_hh,
                                 weff_ih,weff_hh,wt1a,wt1b,wt2);
  k_gemmP<<<256,512,0,stream>>>(x_bf, wt1a, b_t1, P);

  const float* pih = hebb_ih; const float* phh = hebb_hh;
  for (int s=0; s<3; ++s){
    float* nih = (s&1) ? hebB_ih : hebA_ih;
    float* nhh = (s&1) ? hebB_hh : hebA_hh;
    // k1: h_mid = h + 0.5*DT*dynamics(h)
    k_dyn<<<256,512,0,stream>>>(x_bf, h_state, h_state, weff_ih, weff_hh, wt1b, wt2, P,
                                b_ih, b_hh, b_t2, 0.5f*DTF, hmF, hmT, 1);
    // hebb updates (x^T@hm, hm^T@hm) + Weff rebuild
    k_hebb_part<<<256,512,0,stream>>>(xT, hmT, part);
    k_hebb_reduce<<<512,256,0,stream>>>(part, pih, phh, nih, nhh, W_ih, W_hh, weff_ih, weff_hh);
    // k2: h = h + DT*dynamics(h_mid)   (in-place elementwise on h_state)
    k_dyn<<<256,512,0,stream>>>(x_bf, hmF, h_state, weff_ih, weff_hh, wt1b, wt2, P,
                                b_ih, b_hh, b_t2, DTF, h_state, (u16*)0, 0);
    pih = nih; phh = nhh;
  }
}